// Round 1
// baseline (286.911 us; speedup 1.0000x reference)
//
#include <hip/hip_runtime.h>
#include <math.h>

#define Bb 64
#define Nn 512
#define Ff 64
#define Dd 64
#define Kk 20
#define Hh 32
#define ROWS (Bb*Nn)   /* 32768 */
#define EPSc 1e-5f
#define NEG 0.2f

// ---------------- workspace layout (float units) ----------------
// 0       : inv_nrm[512]
// 512     : topk_idx[512*20]  (int)
// 10752   : stats[512]: gsum1[64] gsq1[64] gsum2[64] gsq2[64] A1[64] C1[64] A2[64] C2[64]
// 11264   : a_i[32768]
// 44032   : a_j[32768]
// 76800   : xw[32768*64]
// 2173952 : gnn_out / y (in-place) [32768*64]
// total 4271104 floats = ~16.3 MiB

__global__ void k_init(float* stats) {
    stats[threadIdx.x] = 0.f;   // zero gsum1/gsq1/gsum2/gsq2 (256 floats)
}

__global__ void k_norm(const float* __restrict__ emb, float* __restrict__ inv_nrm) {
    int n = blockIdx.x * blockDim.x + threadIdx.x;
    if (n < Nn) {
        float s = 0.f;
        for (int d = 0; d < Dd; d++) { float v = emb[n*Dd + d]; s += v*v; }
        inv_nrm[n] = 1.f / sqrtf(s);
    }
}

// one block per row i; 256 threads; top-20 argmax with lower-index tie-break
__global__ __launch_bounds__(256) void k_topk(const float* __restrict__ emb,
                                              const float* __restrict__ inv_nrm,
                                              int* __restrict__ topk) {
    __shared__ float wi[Dd];
    __shared__ float sv[Nn];
    __shared__ float rv[256];
    __shared__ int   ri[256];
    int i = blockIdx.x, t = threadIdx.x;
    if (t < Dd) wi[t] = emb[i*Dd + t];
    __syncthreads();
    float inv_i = inv_nrm[i];
    for (int j = t; j < Nn; j += 256) {
        float s = 0.f;
        for (int d = 0; d < Dd; d++) s += wi[d] * emb[j*Dd + d];
        sv[j] = s * inv_i * inv_nrm[j];
    }
    __syncthreads();
    for (int k = 0; k < Kk; k++) {
        float v0 = sv[t], v1 = sv[t+256];
        float bv; int bi;
        if (v1 > v0) { bv = v1; bi = t + 256; } else { bv = v0; bi = t; }
        rv[t] = bv; ri[t] = bi;
        __syncthreads();
        for (int s = 128; s > 0; s >>= 1) {
            if (t < s) {
                float ov = rv[t+s]; int oi = ri[t+s];
                if (ov > rv[t] || (ov == rv[t] && oi < ri[t])) { rv[t] = ov; ri[t] = oi; }
            }
            __syncthreads();
        }
        if (t == 0) { topk[i*Kk + k] = ri[0]; sv[ri[0]] = -INFINITY; }
        __syncthreads();
    }
}

// xw = data @ W^T ; a_i, a_j row scalars.  256 thr = 4 rows x 64 lanes.
__global__ __launch_bounds__(256) void k_xw(const float* __restrict__ data,
                                            const float* __restrict__ emb,
                                            const float* __restrict__ Wg,
                                            const float* __restrict__ att_i,
                                            const float* __restrict__ att_j,
                                            const float* __restrict__ att_em_i,
                                            const float* __restrict__ att_em_j,
                                            float* __restrict__ xw,
                                            float* __restrict__ ai,
                                            float* __restrict__ aj) {
    __shared__ float Wt[Ff*65];      // Wt[f*65+d] = W[d,f]  (pad 65 -> conflict-free)
    __shared__ float sdata[4*64];
    int t = threadIdx.x;
    for (int i = t; i < Dd*Ff; i += 256) {
        int d = i >> 6, f = i & 63;
        Wt[f*65 + d] = Wg[i];
    }
    int row0 = blockIdx.x * 4;
    sdata[t] = data[row0*Ff + t];
    __syncthreads();
    int r = t >> 6, d = t & 63;
    int row = row0 + r;
    float acc = 0.f;
    #pragma unroll
    for (int f = 0; f < Ff; f++) acc += sdata[r*64 + f] * Wt[f*65 + d];
    xw[row*Dd + d] = acc;
    int n = row & (Nn - 1);
    float wv = emb[n*Dd + d];
    float vi = acc*att_i[d] + wv*att_em_i[d];
    float vj = acc*att_j[d] + wv*att_em_j[d];
    #pragma unroll
    for (int s = 32; s > 0; s >>= 1) { vi += __shfl_xor(vi, s, 64); vj += __shfl_xor(vj, s, 64); }
    if (d == 0) { ai[row] = vi; aj[row] = vj; }
}

// attention gather + softmax + weighted sum (+BN1 stats). 256 thr = 4 rows x 64 lanes.
__global__ __launch_bounds__(256) void k_gnn(const float* __restrict__ xw,
                                             const float* __restrict__ ai,
                                             const float* __restrict__ aj,
                                             const int* __restrict__ topk,
                                             const float* __restrict__ bias,
                                             float* __restrict__ gout,
                                             float* __restrict__ stats) {
    int t = threadIdx.x;
    int d = t & 63, r = t >> 6;
    float lsum = 0.f, lsq = 0.f;
    for (int row0 = blockIdx.x*4; row0 < ROWS; row0 += gridDim.x*4) {
        int row = row0 + r;
        int b = row >> 9;
        int n = row & (Nn - 1);
        float aival = ai[row];
        float e[Kk]; int idxs[Kk];
        float m = -INFINITY;
        #pragma unroll
        for (int k = 0; k < Kk; k++) {
            int j = topk[n*Kk + k];
            idxs[k] = j;
            float v = aival + aj[(b << 9) + j];
            v = v > 0.f ? v : NEG * v;
            e[k] = v; m = fmaxf(m, v);
        }
        float s = 0.f;
        #pragma unroll
        for (int k = 0; k < Kk; k++) { e[k] = __expf(e[k] - m); s += e[k]; }
        float invs = 1.f / s;
        float acc = bias[d];
        #pragma unroll
        for (int k = 0; k < Kk; k++)
            acc += e[k] * invs * xw[((b << 9) + idxs[k])*Dd + d];
        gout[row*Dd + d] = acc;
        lsum += acc; lsq += acc*acc;
    }
    __shared__ float ssum[4][64], ssq[4][64];
    ssum[r][d] = lsum; ssq[r][d] = lsq;
    __syncthreads();
    if (t < 64) {
        float s1 = ssum[0][t] + ssum[1][t] + ssum[2][t] + ssum[3][t];
        float s2 = ssq[0][t] + ssq[1][t] + ssq[2][t] + ssq[3][t];
        atomicAdd(&stats[t], s1);
        atomicAdd(&stats[64 + t], s2);
    }
}

// finalize BN: A = istd*g, C = beta - mean*istd*g.  64 threads.
__global__ void k_bnfin(float* stats, const float* __restrict__ g,
                        const float* __restrict__ bta, int which) {
    int d = threadIdx.x;
    float mean = stats[which*128 + d]      * (1.f / ROWS);
    float ex2  = stats[which*128 + 64 + d] * (1.f / ROWS);
    float var  = ex2 - mean*mean;
    float istd = 1.f / sqrtf(var + EPSc);
    float A = istd * g[d];
    stats[256 + which*128 + d]      = A;
    stats[256 + which*128 + 64 + d] = bta[d] - mean * A;
}

// y = relu(bn1(x)) * w   (+BN2 stats); in-place over gout.
__global__ __launch_bounds__(256) void k_bn1mul(float* __restrict__ gout,
                                                const float* __restrict__ emb,
                                                float* __restrict__ stats) {
    int t = threadIdx.x;
    int d = t & 63, r = t >> 6;
    const float A = stats[256 + d], C = stats[320 + d];
    float lsum = 0.f, lsq = 0.f;
    for (int row0 = blockIdx.x*4; row0 < ROWS; row0 += gridDim.x*4) {
        int row = row0 + r;
        int n = row & (Nn - 1);
        float x = gout[row*Dd + d];
        float v = x*A + C;
        v = v > 0.f ? v : 0.f;
        v *= emb[n*Dd + d];
        gout[row*Dd + d] = v;
        lsum += v; lsq += v*v;
    }
    __shared__ float ssum[4][64], ssq[4][64];
    ssum[r][d] = lsum; ssq[r][d] = lsq;
    __syncthreads();
    if (t < 64) {
        float s1 = ssum[0][t] + ssum[1][t] + ssum[2][t] + ssum[3][t];
        float s2 = ssq[0][t] + ssq[1][t] + ssq[2][t] + ssq[3][t];
        atomicAdd(&stats[128 + t], s1);
        atomicAdd(&stats[192 + t], s2);
    }
}

// z = relu(bn2(y)); h = z@linW^T+linb (64->32); o = h@outW^T+outb (32->64)
__global__ __launch_bounds__(256) void k_head(const float* __restrict__ y,
                                              const float* __restrict__ stats,
                                              const float* __restrict__ linW,
                                              const float* __restrict__ linb,
                                              const float* __restrict__ outW,
                                              const float* __restrict__ outb,
                                              float* __restrict__ out) {
    int t = threadIdx.x;
    int d = t & 63, r = t >> 6;
    int row = blockIdx.x*4 + r;
    __shared__ float zsh[4][64];
    __shared__ float hsh[4][32];
    float x = y[row*Dd + d];
    float A = stats[384 + d], C = stats[448 + d];
    float z = x*A + C;
    z = z > 0.f ? z : 0.f;
    zsh[r][d] = z;
    __syncthreads();
    if (d < Hh) {
        float h = linb[d];
        #pragma unroll
        for (int dd = 0; dd < Dd; dd++) h += zsh[r][dd] * linW[d*Dd + dd];
        hsh[r][d] = h;
    }
    __syncthreads();
    float o = outb[d];
    #pragma unroll
    for (int j = 0; j < Hh; j++) o += hsh[r][j] * outW[d*Hh + j];
    out[row*64 + d] = o;
}

extern "C" void kernel_launch(void* const* d_in, const int* in_sizes, int n_in,
                              void* d_out, int out_size, void* d_ws, size_t ws_size,
                              hipStream_t stream) {
    const float* data     = (const float*)d_in[0];
    const float* emb      = (const float*)d_in[2];
    const float* Wg       = (const float*)d_in[3];
    const float* att_i    = (const float*)d_in[4];
    const float* att_j    = (const float*)d_in[5];
    const float* att_em_i = (const float*)d_in[6];
    const float* att_em_j = (const float*)d_in[7];
    const float* bias     = (const float*)d_in[8];
    const float* bn1_g    = (const float*)d_in[9];
    const float* bn1_b    = (const float*)d_in[10];
    const float* bn2_g    = (const float*)d_in[11];
    const float* bn2_b    = (const float*)d_in[12];
    const float* linW     = (const float*)d_in[13];
    const float* linb     = (const float*)d_in[14];
    const float* outW     = (const float*)d_in[15];
    const float* outb     = (const float*)d_in[16];
    float* out = (float*)d_out;

    float* ws       = (float*)d_ws;
    float* inv_nrm  = ws;                 // 512
    int*   topk     = (int*)(ws + 512);   // 10240 ints
    float* stats    = ws + 10752;         // 512
    float* a_i      = ws + 11264;         // 32768
    float* a_j      = ws + 44032;         // 32768
    float* xw       = ws + 76800;         // 2097152
    float* gout     = ws + 2173952;       // 2097152

    k_init <<<1, 256, 0, stream>>>(stats);
    k_norm <<<2, 256, 0, stream>>>(emb, inv_nrm);
    k_topk <<<Nn, 256, 0, stream>>>(emb, inv_nrm, topk);
    k_xw   <<<ROWS/4, 256, 0, stream>>>(data, emb, Wg, att_i, att_j, att_em_i, att_em_j,
                                        xw, a_i, a_j);
    k_gnn  <<<1024, 256, 0, stream>>>(xw, a_i, a_j, topk, bias, gout, stats);
    k_bnfin<<<1, 64, 0, stream>>>(stats, bn1_g, bn1_b, 0);
    k_bn1mul<<<1024, 256, 0, stream>>>(gout, emb, stats);
    k_bnfin<<<1, 64, 0, stream>>>(stats, bn2_g, bn2_b, 1);
    k_head <<<ROWS/4, 256, 0, stream>>>(gout, stats, linW, linb, outW, outb, out);
}

// Round 2
// 222.445 us; speedup vs baseline: 1.2898x; 1.2898x over previous
//
#include <hip/hip_runtime.h>
#include <math.h>

#define Bb 64
#define Nn 512
#define Ff 64
#define Dd 64
#define Kk 20
#define Hh 32
#define ROWS (Bb*Nn)   /* 32768 */
#define EPSc 1e-5f
#define NEG 0.2f

// ---------------- workspace layout (float units) ----------------
// 0       : (unused)
// 512     : topk_idx[512*20]  (int)
// 10752   : stats[512]: gsum1[64] gsq1[64] gsum2[64] gsq2[64] A1[64] C1[64] A2[64] C2[64]
// 11264   : a_i[32768]
// 44032   : a_j[32768]
// 76800   : xw[32768*64]
// 2173952 : gnn_out / y (in-place) [32768*64]

__device__ __forceinline__ float dot4(float4 a, float4 b) {
    return a.x*b.x + a.y*b.y + a.z*b.z + a.w*b.w;
}

// One block per row i. Fused: norm(i) + cosine scores (coalesced float4, 4 lanes/row)
// + single-wave register top-20 (lower-index tie-break).  Block 0 also zeros stats.
__global__ __launch_bounds__(256) void k_topk(const float* __restrict__ emb,
                                              int* __restrict__ topk,
                                              float* __restrict__ stats) {
    __shared__ __align__(16) float wish[64];
    __shared__ float sv[512];
    int i = blockIdx.x, t = threadIdx.x;
    if (i == 0) stats[t] = (t < 256) ? 0.f : stats[t];   // zero accumulators
    if (t < 64) {
        float wv = emb[i*64 + t];
        float ss = wv*wv;
        #pragma unroll
        for (int s = 32; s > 0; s >>= 1) ss += __shfl_xor(ss, s);
        wish[t] = wv * (1.f / sqrtf(ss));
    }
    __syncthreads();
    int seg = t & 3;        // which 16-element segment of the dot
    int jl  = t >> 2;       // 0..63 : row within tile
    const float4* wish4 = (const float4*)wish;
    float4 wn[4];
    #pragma unroll
    for (int q = 0; q < 4; q++) wn[q] = wish4[seg*4 + q];
    const float4* emb4 = (const float4*)emb;
    for (int jb = 0; jb < 8; jb++) {
        int j = jb*64 + jl;
        float p = 0.f, s2 = 0.f;
        #pragma unroll
        for (int q = 0; q < 4; q++) {
            float4 e = emb4[j*16 + seg*4 + q];
            p  += dot4(e, wn[q]);
            s2 += dot4(e, e);
        }
        p  += __shfl_xor(p, 1);  p  += __shfl_xor(p, 2);
        s2 += __shfl_xor(s2, 1); s2 += __shfl_xor(s2, 2);
        if (seg == 0) sv[j] = p * (1.f / sqrtf(s2));
    }
    __syncthreads();
    if (t < 64) {           // single-wave top-20, no barriers
        float v[8];
        #pragma unroll
        for (int q = 0; q < 8; q++) v[q] = sv[q*64 + t];
        for (int k = 0; k < Kk; k++) {
            float bv = v[0]; int bi = t;
            #pragma unroll
            for (int q = 1; q < 8; q++)
                if (v[q] > bv) { bv = v[q]; bi = q*64 + t; }   // ties -> lower idx
            #pragma unroll
            for (int s = 1; s < 64; s <<= 1) {
                float ov = __shfl_xor(bv, s); int oi = __shfl_xor(bi, s);
                if (ov > bv || (ov == bv && oi < bi)) { bv = ov; bi = oi; }
            }
            if (t == 0) topk[i*Kk + k] = bi;
            #pragma unroll
            for (int q = 0; q < 8; q++)
                if (bi == q*64 + t) v[q] = -INFINITY;
        }
    }
}

// xw = data @ W^T ; a_i, a_j.  W row held in registers (64 VGPR), data row via
// LDS broadcast float4.  1024 blocks x 8 grid-stride iters, 4 rows/iter.
__global__ __launch_bounds__(256) void k_xw(const float* __restrict__ data,
                                            const float* __restrict__ emb,
                                            const float* __restrict__ Wg,
                                            const float* __restrict__ att_i,
                                            const float* __restrict__ att_j,
                                            const float* __restrict__ att_em_i,
                                            const float* __restrict__ att_em_j,
                                            float* __restrict__ xw,
                                            float* __restrict__ ai,
                                            float* __restrict__ aj) {
    __shared__ __align__(16) float sh[256];
    int t = threadIdx.x;
    int d = t & 63, r = t >> 6;
    const float4* wg4 = (const float4*)Wg;
    float4 w4[16];
    #pragma unroll
    for (int q = 0; q < 16; q++) w4[q] = wg4[d*16 + q];   // W[d][:] once per block
    float atti = att_i[d], attj = att_j[d];
    float aemi = att_em_i[d], aemj = att_em_j[d];
    const float4* sh4 = (const float4*)sh;
    for (int g = blockIdx.x; g < ROWS/4; g += 1024) {
        sh[t] = data[g*256 + t];
        __syncthreads();
        float acc = 0.f;
        #pragma unroll
        for (int q = 0; q < 16; q++) acc += dot4(sh4[r*16 + q], w4[q]);  // broadcast reads
        int row = g*4 + r;
        xw[row*64 + d] = acc;
        int n = row & (Nn - 1);
        float wv = emb[n*64 + d];
        float vi = acc*atti + wv*aemi;
        float vj = acc*attj + wv*aemj;
        #pragma unroll
        for (int s = 32; s > 0; s >>= 1) { vi += __shfl_xor(vi, s); vj += __shfl_xor(vj, s); }
        if (d == 0) { ai[row] = vi; aj[row] = vj; }
        __syncthreads();
    }
}

// attention gather + softmax + weighted sum (+BN1 stats).
// XCD-contiguous mapping: XCD x handles rows [x*4096, x*4096+4096) -> its L2
// holds only 8 batches' xw slices (~1MB).
__global__ __launch_bounds__(256) void k_gnn(const float* __restrict__ xw,
                                             const float* __restrict__ ai,
                                             const float* __restrict__ aj,
                                             const int* __restrict__ topk,
                                             const float* __restrict__ bias,
                                             float* __restrict__ gout,
                                             float* __restrict__ stats) {
    int t = threadIdx.x;
    int d = t & 63, r = t >> 6;
    int xcd = blockIdx.x & 7, sub = blockIdx.x >> 3;
    float bias_d = bias[d];
    float lsum = 0.f, lsq = 0.f;
    for (int it = 0; it < 8; it++) {
        int g = xcd*1024 + it*128 + sub;
        int row = g*4 + r;
        int b = row >> 9;
        int n = row & (Nn - 1);
        float aival = ai[row];
        float e[Kk]; int idxs[Kk];
        float m = -INFINITY;
        #pragma unroll
        for (int k = 0; k < Kk; k++) {
            int j = topk[n*Kk + k];
            idxs[k] = j;
            float v = aival + aj[(b << 9) + j];
            v = v > 0.f ? v : NEG * v;
            e[k] = v; m = fmaxf(m, v);
        }
        float s = 0.f;
        #pragma unroll
        for (int k = 0; k < Kk; k++) { e[k] = __expf(e[k] - m); s += e[k]; }
        float invs = 1.f / s;
        float acc = bias_d;
        #pragma unroll
        for (int k = 0; k < Kk; k++)
            acc += e[k] * invs * xw[((b << 9) + idxs[k])*64 + d];
        gout[row*64 + d] = acc;
        lsum += acc; lsq += acc*acc;
    }
    __shared__ float ssum[4][64], ssq[4][64];
    ssum[r][d] = lsum; ssq[r][d] = lsq;
    __syncthreads();
    if (t < 64) {
        float s1 = ssum[0][t] + ssum[1][t] + ssum[2][t] + ssum[3][t];
        float s2 = ssq[0][t] + ssq[1][t] + ssq[2][t] + ssq[3][t];
        atomicAdd(&stats[t], s1);
        atomicAdd(&stats[64 + t], s2);
    }
}

// finalize BN: A = istd*g, C = beta - mean*istd*g.  64 threads.
__global__ void k_bnfin(float* stats, const float* __restrict__ g,
                        const float* __restrict__ bta, int which) {
    int d = threadIdx.x;
    float mean = stats[which*128 + d]      * (1.f / ROWS);
    float ex2  = stats[which*128 + 64 + d] * (1.f / ROWS);
    float var  = ex2 - mean*mean;
    float istd = 1.f / sqrtf(var + EPSc);
    float A = istd * g[d];
    stats[256 + which*128 + d]      = A;
    stats[256 + which*128 + 64 + d] = bta[d] - mean * A;
}

// y = relu(bn1(x)) * w   (+BN2 stats); in-place over gout.
__global__ __launch_bounds__(256) void k_bn1mul(float* __restrict__ gout,
                                                const float* __restrict__ emb,
                                                float* __restrict__ stats) {
    int t = threadIdx.x;
    int d = t & 63, r = t >> 6;
    const float A = stats[256 + d], C = stats[320 + d];
    float lsum = 0.f, lsq = 0.f;
    for (int row0 = blockIdx.x*4; row0 < ROWS; row0 += gridDim.x*4) {
        int row = row0 + r;
        int n = row & (Nn - 1);
        float x = gout[row*64 + d];
        float v = x*A + C;
        v = v > 0.f ? v : 0.f;
        v *= emb[n*64 + d];
        gout[row*64 + d] = v;
        lsum += v; lsq += v*v;
    }
    __shared__ float ssum[4][64], ssq[4][64];
    ssum[r][d] = lsum; ssq[r][d] = lsq;
    __syncthreads();
    if (t < 64) {
        float s1 = ssum[0][t] + ssum[1][t] + ssum[2][t] + ssum[3][t];
        float s2 = ssq[0][t] + ssq[1][t] + ssq[2][t] + ssq[3][t];
        atomicAdd(&stats[128 + t], s1);
        atomicAdd(&stats[192 + t], s2);
    }
}

// z = relu(bn2(y)); h = z@linW^T+linb (64->32); o = h@outW^T+outb (32->64).
// Weights persistent in VGPRs; z/h exchanged via LDS broadcast + shfl.
__global__ __launch_bounds__(256) void k_head(const float* __restrict__ y,
                                              const float* __restrict__ stats,
                                              const float* __restrict__ linW,
                                              const float* __restrict__ linb,
                                              const float* __restrict__ outW,
                                              const float* __restrict__ outb,
                                              float* __restrict__ out) {
    __shared__ __align__(16) float zsh[4][64];
    __shared__ __align__(16) float hsh[4][32];
    int t = threadIdx.x;
    int d = t & 63, r = t >> 6;
    int j = d & 31, half = d >> 5;
    float A = stats[384 + d], C = stats[448 + d];
    const float4* linW4 = (const float4*)linW;
    const float4* outW4 = (const float4*)outW;
    float4 lw4[8], ow4[8];
    #pragma unroll
    for (int q = 0; q < 8; q++) lw4[q] = linW4[j*16 + half*8 + q];  // linW[j][half*32..]
    #pragma unroll
    for (int q = 0; q < 8; q++) ow4[q] = outW4[d*8 + q];            // outW[d][:]
    float lb = linb[j], ob = outb[d];
    const float4* zsh4 = (const float4*)zsh;
    const float4* hsh4 = (const float4*)hsh;
    for (int g = blockIdx.x; g < ROWS/4; g += 512) {
        int row = g*4 + r;
        float x = y[row*64 + d];
        float z = fmaxf(x*A + C, 0.f);
        zsh[r][d] = z;
        __syncthreads();
        float p = 0.f;
        #pragma unroll
        for (int q = 0; q < 8; q++) p += dot4(zsh4[r*16 + half*8 + q], lw4[q]);
        p += __shfl_xor(p, 32);            // combine halves of the 64-dot
        float h = p + lb;
        if (half == 0) hsh[r][j] = h;
        __syncthreads();
        float o = ob;
        #pragma unroll
        for (int q = 0; q < 8; q++) o += dot4(hsh4[r*8 + q], ow4[q]);
        out[row*64 + d] = o;
        __syncthreads();
    }
}

extern "C" void kernel_launch(void* const* d_in, const int* in_sizes, int n_in,
                              void* d_out, int out_size, void* d_ws, size_t ws_size,
                              hipStream_t stream) {
    const float* data     = (const float*)d_in[0];
    const float* emb      = (const float*)d_in[2];
    const float* Wg       = (const float*)d_in[3];
    const float* att_i    = (const float*)d_in[4];
    const float* att_j    = (const float*)d_in[5];
    const float* att_em_i = (const float*)d_in[6];
    const float* att_em_j = (const float*)d_in[7];
    const float* bias     = (const float*)d_in[8];
    const float* bn1_g    = (const float*)d_in[9];
    const float* bn1_b    = (const float*)d_in[10];
    const float* bn2_g    = (const float*)d_in[11];
    const float* bn2_b    = (const float*)d_in[12];
    const float* linW     = (const float*)d_in[13];
    const float* linb     = (const float*)d_in[14];
    const float* outW     = (const float*)d_in[15];
    const float* outb     = (const float*)d_in[16];
    float* out = (float*)d_out;

    float* ws       = (float*)d_ws;
    int*   topk     = (int*)(ws + 512);   // 10240 ints
    float* stats    = ws + 10752;         // 512
    float* a_i      = ws + 11264;         // 32768
    float* a_j      = ws + 44032;         // 32768
    float* xw       = ws + 76800;         // 2097152
    float* gout     = ws + 2173952;       // 2097152

    k_topk  <<<Nn, 256, 0, stream>>>(emb, topk, stats);
    k_xw    <<<1024, 256, 0, stream>>>(data, emb, Wg, att_i, att_j, att_em_i, att_em_j,
                                       xw, a_i, a_j);
    k_gnn   <<<1024, 256, 0, stream>>>(xw, a_i, a_j, topk, bias, gout, stats);
    k_bnfin <<<1, 64, 0, stream>>>(stats, bn1_g, bn1_b, 0);
    k_bn1mul<<<1024, 256, 0, stream>>>(gout, emb, stats);
    k_bnfin <<<1, 64, 0, stream>>>(stats, bn2_g, bn2_b, 1);
    k_head  <<<512, 256, 0, stream>>>(gout, stats, linW, linb, outW, outb, out);
}